// Round 1
// baseline (1024.330 us; speedup 1.0000x reference)
//
#include <hip/hip_runtime.h>
#include <math.h>

typedef __bf16 bf16;
typedef __bf16 bf16x8 __attribute__((ext_vector_type(8)));
typedef __bf16 bf16x4 __attribute__((ext_vector_type(4)));
typedef float f32x4 __attribute__((ext_vector_type(4)));

__device__ __forceinline__ float sigmoid_(float x) { return 1.f / (1.f + __expf(-x)); }

// ---------------- generic bf16 GEMM, B in (N,K) "B^T" layout ----------------
enum { M_F32 = 0, M_BF16 = 1, M_BF16_RELU = 2, M_SIG = 3, M_SIG_NEG = 4, M_TANH = 5, M_QUV = 6 };

struct GemmP {
  const bf16* A; const bf16* B;
  bf16* Cb; bf16* Cb2; float* Cf;
  const float* bias; const float* up; const float* vp;
  int K, lda, ldb, ldc;
  long long Abat, Bbat, Cbat;
  int mode;
};

__global__ __launch_bounds__(256, 2) void gemm_bt(GemmP p) {
  const int tid = threadIdx.x;
  const int wave = tid >> 6, lane = tid & 63;
  const int g = lane >> 4, ln = lane & 15;
  const int wr = wave >> 1, wc = wave & 1;
  const bf16* A = p.A + (long long)blockIdx.z * p.Abat;
  const bf16* B = p.B + (long long)blockIdx.z * p.Bbat;
  const int m0 = blockIdx.x * 128, n0 = blockIdx.y * 128;
  __shared__ bf16 As[128 * 40];
  __shared__ bf16 Bs[128 * 40];
  f32x4 acc[4][4] = {};
  for (int k0 = 0; k0 < p.K; k0 += 32) {
    __syncthreads();
#pragma unroll
    for (int j = 0; j < 2; j++) {
      int c = tid + 256 * j;
      int m = c >> 2, k8 = (c & 3) * 8;
      *(bf16x8*)(As + m * 40 + k8) = *(const bf16x8*)(A + (long long)(m0 + m) * p.lda + k0 + k8);
      *(bf16x8*)(Bs + m * 40 + k8) = *(const bf16x8*)(B + (long long)(n0 + m) * p.ldb + k0 + k8);
    }
    __syncthreads();
    bf16x8 af[4], bfm[4];
#pragma unroll
    for (int mi = 0; mi < 4; mi++) af[mi] = *(const bf16x8*)(As + (wr * 64 + mi * 16 + ln) * 40 + g * 8);
#pragma unroll
    for (int ni = 0; ni < 4; ni++) bfm[ni] = *(const bf16x8*)(Bs + (wc * 64 + ni * 16 + ln) * 40 + g * 8);
#pragma unroll
    for (int mi = 0; mi < 4; mi++)
#pragma unroll
      for (int ni = 0; ni < 4; ni++)
        acc[mi][ni] = __builtin_amdgcn_mfma_f32_16x16x32_bf16(af[mi], bfm[ni], acc[mi][ni], 0, 0, 0);
  }
  const long long cb = (long long)blockIdx.z * p.Cbat;
#pragma unroll
  for (int mi = 0; mi < 4; mi++) {
#pragma unroll
    for (int r = 0; r < 4; r++) {
      int row = m0 + wr * 64 + mi * 16 + g * 4 + r;
      long long ro = cb + (long long)row * p.ldc;
#pragma unroll
      for (int ni = 0; ni < 4; ni++) {
        int col = n0 + wc * 64 + ni * 16 + ln;
        float a = acc[mi][ni][r];
        float bv = p.bias ? p.bias[col] : 0.f;
        switch (p.mode) {
          case M_F32: p.Cf[ro + col] = a + bv; break;
          case M_BF16: p.Cb[ro + col] = (bf16)(a + bv); break;
          case M_BF16_RELU: { float t = a + bv; p.Cb[ro + col] = (bf16)(t > 0.f ? t : 0.f); } break;
          case M_SIG: p.Cf[ro + col] = sigmoid_(a + bv); break;
          case M_SIG_NEG: p.Cf[ro + col] = sigmoid_(a - bv); break;
          case M_TANH: p.Cf[ro + col] = tanhf(a + bv); break;
          case M_QUV: {
            float t = a + bv;
            p.Cb[ro + col] = (bf16)(t + p.up[col]);
            p.Cb2[ro + col] = (bf16)(t + p.vp[col]);
          } break;
        }
      }
    }
  }
}

// ---------------- weight transpose + fp32->bf16 convert ----------------
struct TDesc { const float* src; bf16* dst; int K, N, ldd; };
struct TPack { TDesc d[18]; };

__global__ __launch_bounds__(256) void wt_transpose(TPack tp) {
  TDesc t = tp.d[blockIdx.z];
  int ntx = t.N >> 6, nty = t.K >> 6;
  int tile = blockIdx.x;
  if (tile >= ntx * nty) return;
  int k0 = (tile / ntx) * 64, n0 = (tile % ntx) * 64;
  __shared__ bf16 tb[64][72];
  int tid = threadIdx.x;
  int tr = tid >> 4, tc = (tid & 15) * 4;
#pragma unroll
  for (int ph = 0; ph < 4; ph++) {
    int k = k0 + ph * 16 + tr;
    float4 vv = *(const float4*)(t.src + (size_t)k * t.N + n0 + tc);
    tb[tc + 0][ph * 16 + tr] = (bf16)vv.x;
    tb[tc + 1][ph * 16 + tr] = (bf16)vv.y;
    tb[tc + 2][ph * 16 + tr] = (bf16)vv.z;
    tb[tc + 3][ph * 16 + tr] = (bf16)vv.w;
  }
  __syncthreads();
#pragma unroll
  for (int ph = 0; ph < 4; ph++) {
    int n = ph * 16 + tr;
    bf16x4 o;
    o[0] = tb[n][tc + 0]; o[1] = tb[n][tc + 1]; o[2] = tb[n][tc + 2]; o[3] = tb[n][tc + 3];
    *(bf16x4*)(t.dst + (size_t)(n0 + n) * t.ldd + k0 + tc) = o;
  }
}

__global__ void convertf2b(const float* src, bf16* dst, int n) {
  int i = (blockIdx.x * 256 + threadIdx.x) * 4;
  if (i >= n) return;
  float4 vv = *(const float4*)(src + i);
  bf16x4 o; o[0] = (bf16)vv.x; o[1] = (bf16)vv.y; o[2] = (bf16)vv.z; o[3] = (bf16)vv.w;
  *(bf16x4*)(dst + i) = o;
}

// ---------------- LayerNorm 1 (concat(memory, inputs)) ----------------
__global__ __launch_bounds__(256) void ln1_kernel(const float* inputs, const float* memory,
                                                  const float* g, const float* b,
                                                  bf16* x1, bf16* acat1x) {
  int row = blockIdx.x;  // t*4+b over FULL*BS = 4096
  int tid = threadIdx.x;
  const float* src = (row < 2048) ? (memory + (size_t)row * 1024)
                                  : (inputs + (size_t)(row - 2048) * 1024);
  float4 vv = *(const float4*)(src + tid * 4);
  float s = vv.x + vv.y + vv.z + vv.w;
  float s2 = vv.x * vv.x + vv.y * vv.y + vv.z * vv.z + vv.w * vv.w;
#pragma unroll
  for (int off = 1; off < 64; off <<= 1) { s += __shfl_xor(s, off, 64); s2 += __shfl_xor(s2, off, 64); }
  __shared__ float red[8];
  int wave = tid >> 6, lane = tid & 63;
  if (lane == 0) { red[wave] = s; red[4 + wave] = s2; }
  __syncthreads();
  s = red[0] + red[1] + red[2] + red[3];
  s2 = red[4] + red[5] + red[6] + red[7];
  float mean = s * (1.f / 1024.f);
  float var = s2 * (1.f / 1024.f) - mean * mean;
  float rstd = rsqrtf(var + 1e-5f);
  float4 gv = *(const float4*)(g + tid * 4);
  float4 bv = *(const float4*)(b + tid * 4);
  bf16x4 o;
  o[0] = (bf16)((vv.x - mean) * rstd * gv.x + bv.x);
  o[1] = (bf16)((vv.y - mean) * rstd * gv.y + bv.y);
  o[2] = (bf16)((vv.z - mean) * rstd * gv.z + bv.z);
  o[3] = (bf16)((vv.w - mean) * rstd * gv.w + bv.w);
  *(bf16x4*)(x1 + (size_t)row * 1024 + tid * 4) = o;
  if (row >= 2048) {  // raw inputs bf16 into Acat1 cols [1024,2048)
    bf16x4 xo;
    xo[0] = (bf16)vv.x; xo[1] = (bf16)vv.y; xo[2] = (bf16)vv.z; xo[3] = (bf16)vv.w;
    *(bf16x4*)(acat1x + (size_t)(row - 2048) * 2048 + tid * 4) = xo;
  }
}

// ---------------- V transpose: value(t,b,h,d) -> vT[(b,h,d), t] ----------------
__global__ __launch_bounds__(256) void transpose_v(const bf16* kvb, bf16* vT) {
  int bh = blockIdx.y;
  int b = bh >> 4, h = bh & 15;
  int t0 = blockIdx.x * 64;
  __shared__ bf16 tile[64][72];
  int tid = threadIdx.x;
  int tr = tid >> 4, tc = (tid & 15) * 4;
#pragma unroll
  for (int ph = 0; ph < 4; ph++) {
    int t = t0 + ph * 16 + tr;
    const bf16* src = kvb + ((size_t)t * 4 + b) * 2048 + 1024 + h * 64 + tc;
    bf16x4 vv = *(const bf16x4*)src;
    tile[tc + 0][ph * 16 + tr] = vv[0];
    tile[tc + 1][ph * 16 + tr] = vv[1];
    tile[tc + 2][ph * 16 + tr] = vv[2];
    tile[tc + 3][ph * 16 + tr] = vv[3];
  }
  __syncthreads();
#pragma unroll
  for (int ph = 0; ph < 4; ph++) {
    int d = ph * 16 + tr;
    bf16x4 o;
    o[0] = tile[d][tc + 0]; o[1] = tile[d][tc + 1]; o[2] = tile[d][tc + 2]; o[3] = tile[d][tc + 3];
    *(bf16x4*)(vT + ((size_t)bh * 64 + d) * 1024 + t0 + tc) = o;
  }
}

// ---------------- fused rel-pos flash attention ----------------
// grid (qblock=8, bh=64); 4 waves, wave owns 16 q rows. rel_shift folded into
// a shifted contiguous read of B_pos[q, k+511-q]; wrap region == causal mask.
__global__ __launch_bounds__(256) void flash_attn(const bf16* qu, const bf16* kmat,
                                                  const bf16* vT, const bf16* bpos, bf16* av) {
  int qb = blockIdx.x;
  int bh = blockIdx.y;
  int b = bh >> 4, h = bh & 15;
  int tid = threadIdx.x;
  int wave = tid >> 6, lane = tid & 63;
  int g = lane >> 4, ln = lane & 15;
  int q0w = qb * 64 + wave * 16;

  const bf16* qubase = qu + ((size_t)(q0w + ln) * 4 + b) * 1024 + h * 64;
  bf16x8 aqu0 = *(const bf16x8*)(qubase + g * 8);
  bf16x8 aqu1 = *(const bf16x8*)(qubase + 32 + g * 8);

  const bf16* bprow[4];
#pragma unroll
  for (int r = 0; r < 4; r++) {
    int q = q0w + g * 4 + r;
    bprow[r] = bpos + ((size_t)h * 2048 + (size_t)q * 4 + b) * 1024;
  }

  f32x4 o[4] = {};
  float mrow[4] = {-1e30f, -1e30f, -1e30f, -1e30f};
  float lrow[4] = {0.f, 0.f, 0.f, 0.f};

  __shared__ bf16 Pld[4][16][64];

  int nk = qb + 9;  // covers k <= q0+575
  for (int kt = 0; kt < nk; kt++) {
    int k0 = kt * 64;
    __syncthreads();
    f32x4 S[4];
#pragma unroll
    for (int s = 0; s < 4; s++) {
      const bf16* kbase = kmat + ((size_t)(k0 + s * 16 + ln) * 4 + b) * 2048 + h * 64;
      bf16x8 bk0 = *(const bf16x8*)(kbase + g * 8);
      bf16x8 bk1 = *(const bf16x8*)(kbase + 32 + g * 8);
      f32x4 c = {0.f, 0.f, 0.f, 0.f};
      c = __builtin_amdgcn_mfma_f32_16x16x32_bf16(aqu0, bk0, c, 0, 0, 0);
      c = __builtin_amdgcn_mfma_f32_16x16x32_bf16(aqu1, bk1, c, 0, 0, 0);
      S[s] = c;
    }
    float mt[4];
#pragma unroll
    for (int r = 0; r < 4; r++) {
      int q = q0w + g * 4 + r;
      float mx = -1e30f;
#pragma unroll
      for (int s = 0; s < 4; s++) {
        int k = k0 + s * 16 + ln;
        float val;
        if (k <= q + 512) {
          val = (S[s][r] + (float)bprow[r][k + 511 - q]) * 0.125f;
        } else {
          val = -1e30f;
        }
        S[s][r] = val;
        mx = fmaxf(mx, val);
      }
      mt[r] = mx;
    }
#pragma unroll
    for (int offx = 1; offx < 16; offx <<= 1)
#pragma unroll
      for (int r = 0; r < 4; r++) mt[r] = fmaxf(mt[r], __shfl_xor(mt[r], offx, 64));
    float alpha[4], ls[4];
#pragma unroll
    for (int r = 0; r < 4; r++) {
      float mn = fmaxf(mrow[r], mt[r]);
      alpha[r] = __expf(mrow[r] - mn);
      mrow[r] = mn;
      ls[r] = 0.f;
    }
#pragma unroll
    for (int s = 0; s < 4; s++)
#pragma unroll
      for (int r = 0; r < 4; r++) {
        float pv = __expf(S[s][r] - mrow[r]);
        S[s][r] = pv;
        ls[r] += pv;
      }
#pragma unroll
    for (int offx = 1; offx < 16; offx <<= 1)
#pragma unroll
      for (int r = 0; r < 4; r++) ls[r] += __shfl_xor(ls[r], offx, 64);
#pragma unroll
    for (int r = 0; r < 4; r++) lrow[r] = lrow[r] * alpha[r] + ls[r];
#pragma unroll
    for (int ni = 0; ni < 4; ni++)
#pragma unroll
      for (int r = 0; r < 4; r++) o[ni][r] *= alpha[r];
    // P: C-layout -> LDS -> A-layout
#pragma unroll
    for (int s = 0; s < 4; s++)
#pragma unroll
      for (int r = 0; r < 4; r++)
        Pld[wave][g * 4 + r][s * 16 + ln] = (bf16)S[s][r];
    __syncthreads();
    bf16x8 pa0 = *(const bf16x8*)&Pld[wave][ln][g * 8];
    bf16x8 pa1 = *(const bf16x8*)&Pld[wave][ln][32 + g * 8];
#pragma unroll
    for (int ni = 0; ni < 4; ni++) {
      const bf16* vbase = vT + ((size_t)bh * 64 + ni * 16 + ln) * 1024 + k0;
      bf16x8 bv0 = *(const bf16x8*)(vbase + g * 8);
      bf16x8 bv1 = *(const bf16x8*)(vbase + 32 + g * 8);
      o[ni] = __builtin_amdgcn_mfma_f32_16x16x32_bf16(pa0, bv0, o[ni], 0, 0, 0);
      o[ni] = __builtin_amdgcn_mfma_f32_16x16x32_bf16(pa1, bv1, o[ni], 0, 0, 0);
    }
  }
#pragma unroll
  for (int r = 0; r < 4; r++) {
    int q = q0w + g * 4 + r;
    float inv = 1.f / lrow[r];
    bf16* dst = av + ((size_t)q * 4 + b) * 1024 + h * 64;
#pragma unroll
    for (int ni = 0; ni < 4; ni++) dst[ni * 16 + ln] = (bf16)(o[ni][r] * inv);
  }
}

// ---------------- elementwise ----------------
__global__ void rx_kernel(const float* r, const float* x, bf16* dst, int n) {
  int i = (blockIdx.x * 256 + threadIdx.x) * 4;
  if (i >= n) return;
  float4 rv = *(const float4*)(r + i);
  float4 xv = *(const float4*)(x + i);
  int row = i >> 10, c = i & 1023;
  bf16x4 o;
  o[0] = (bf16)(rv.x * xv.x); o[1] = (bf16)(rv.y * xv.y);
  o[2] = (bf16)(rv.z * xv.z); o[3] = (bf16)(rv.w * xv.w);
  *(bf16x4*)(dst + (size_t)row * 2048 + c) = o;
}

__global__ __launch_bounds__(256) void gru_combine_ln(const float* z, const float* h, const float* x,
                                                      const float* g, const float* b,
                                                      float* o1, bf16* x2, bf16* o1b) {
  int row = blockIdx.x, tid = threadIdx.x;
  size_t base = (size_t)row * 1024 + tid * 4;
  float4 zv = *(const float4*)(z + base);
  float4 hv = *(const float4*)(h + base);
  float4 xv = *(const float4*)(x + base);
  float4 ov;
  ov.x = (1.f - zv.x) * xv.x + zv.x * hv.x;
  ov.y = (1.f - zv.y) * xv.y + zv.y * hv.y;
  ov.z = (1.f - zv.z) * xv.z + zv.z * hv.z;
  ov.w = (1.f - zv.w) * xv.w + zv.w * hv.w;
  *(float4*)(o1 + base) = ov;
  bf16x4 ob; ob[0] = (bf16)ov.x; ob[1] = (bf16)ov.y; ob[2] = (bf16)ov.z; ob[3] = (bf16)ov.w;
  *(bf16x4*)(o1b + (size_t)row * 2048 + tid * 4) = ob;
  float s = ov.x + ov.y + ov.z + ov.w;
  float s2 = ov.x * ov.x + ov.y * ov.y + ov.z * ov.z + ov.w * ov.w;
#pragma unroll
  for (int off = 1; off < 64; off <<= 1) { s += __shfl_xor(s, off, 64); s2 += __shfl_xor(s2, off, 64); }
  __shared__ float red[8];
  int wave = tid >> 6, lane = tid & 63;
  if (lane == 0) { red[wave] = s; red[4 + wave] = s2; }
  __syncthreads();
  s = red[0] + red[1] + red[2] + red[3];
  s2 = red[4] + red[5] + red[6] + red[7];
  float mean = s * (1.f / 1024.f);
  float var = s2 * (1.f / 1024.f) - mean * mean;
  float rstd = rsqrtf(var + 1e-5f);
  float4 gv = *(const float4*)(g + tid * 4);
  float4 bv = *(const float4*)(b + tid * 4);
  bf16x4 xo;
  xo[0] = (bf16)((ov.x - mean) * rstd * gv.x + bv.x);
  xo[1] = (bf16)((ov.y - mean) * rstd * gv.y + bv.y);
  xo[2] = (bf16)((ov.z - mean) * rstd * gv.z + bv.z);
  xo[3] = (bf16)((ov.w - mean) * rstd * gv.w + bv.w);
  *(bf16x4*)(x2 + base) = xo;
}

__global__ void final_combine(const float* z, const float* h, const float* o1, float* out, int n) {
  int i = (blockIdx.x * 256 + threadIdx.x) * 4;
  if (i >= n) return;
  float4 zv = *(const float4*)(z + i);
  float4 hv = *(const float4*)(h + i);
  float4 xv = *(const float4*)(o1 + i);
  float4 o;
  o.x = (1.f - zv.x) * xv.x + zv.x * hv.x;
  o.y = (1.f - zv.y) * xv.y + zv.y * hv.y;
  o.z = (1.f - zv.z) * xv.z + zv.z * hv.z;
  o.w = (1.f - zv.w) * xv.w + zv.w * hv.w;
  *(float4*)(out + i) = o;
}

// ---------------- host ----------------
extern "C" void kernel_launch(void* const* d_in, const int* in_sizes, int n_in,
                              void* d_out, int out_size, void* d_ws, size_t ws_size,
                              hipStream_t stream) {
  (void)in_sizes; (void)n_in; (void)out_size; (void)ws_size;
  const float* inputs  = (const float*)d_in[0];
  const float* memory  = (const float*)d_in[1];
  const float* pos_emb = (const float*)d_in[2];
  const float* u_in    = (const float*)d_in[3];
  const float* v_in    = (const float*)d_in[4];
  const float* W_kv    = (const float*)d_in[5];
  const float* b_kv    = (const float*)d_in[6];
  const float* W_q     = (const float*)d_in[7];
  const float* b_q     = (const float*)d_in[8];
  const float* W_proj  = (const float*)d_in[9];
  const float* b_proj  = (const float*)d_in[10];
  const float* W_pos   = (const float*)d_in[11];
  const float* b_pos   = (const float*)d_in[12];
  const float* ln1_g   = (const float*)d_in[13];
  const float* ln1_b   = (const float*)d_in[14];
  const float* ln2_g   = (const float*)d_in[15];
  const float* ln2_b   = (const float*)d_in[16];
  const float* Wr1 = (const float*)d_in[17];
  const float* Ur1 = (const float*)d_in[18];
  const float* Wz1 = (const float*)d_in[19];
  const float* Uz1 = (const float*)d_in[20];
  const float* Wg1 = (const float*)d_in[21];
  const float* Ug1 = (const float*)d_in[22];
  const float* bg1 = (const float*)d_in[23];
  const float* Wr2 = (const float*)d_in[24];
  const float* Ur2 = (const float*)d_in[25];
  const float* Wz2 = (const float*)d_in[26];
  const float* Uz2 = (const float*)d_in[27];
  const float* Wg2 = (const float*)d_in[28];
  const float* Ug2 = (const float*)d_in[29];
  const float* bg2 = (const float*)d_in[30];
  const float* W1  = (const float*)d_in[31];
  const float* b1  = (const float*)d_in[32];
  const float* W2  = (const float*)d_in[33];
  const float* b2  = (const float*)d_in[34];

  char* ws = (char*)d_ws;
  size_t off = 0;
  auto alloc = [&](size_t bytes) -> char* {
    char* p = ws + off;
    off += (bytes + 255) & ~(size_t)255;
    return p;
  };
  bf16* x1      = (bf16*)alloc(4096ull * 1024 * 2);
  bf16* Wkv_t   = (bf16*)alloc(2048ull * 1024 * 2);
  bf16* Wq_t    = (bf16*)alloc(1024ull * 1024 * 2);
  bf16* Wpos_t  = (bf16*)alloc(1024ull * 1024 * 2);
  bf16* Wproj_t = (bf16*)alloc(1024ull * 1024 * 2);
  bf16* Wrc1    = (bf16*)alloc(1024ull * 2048 * 2);
  bf16* Wzc1    = (bf16*)alloc(1024ull * 2048 * 2);
  bf16* Wgc1    = (bf16*)alloc(1024ull * 2048 * 2);
  bf16* Wrc2    = (bf16*)alloc(1024ull * 2048 * 2);
  bf16* Wzc2    = (bf16*)alloc(1024ull * 2048 * 2);
  bf16* Wgc2    = (bf16*)alloc(1024ull * 2048 * 2);
  bf16* W1t     = (bf16*)alloc(4096ull * 1024 * 2);
  bf16* W2t     = (bf16*)alloc(1024ull * 4096 * 2);
  bf16* posb    = (bf16*)alloc(1024ull * 1024 * 2);
  bf16* kvb     = (bf16*)alloc(4096ull * 2048 * 2);
  bf16* qu      = (bf16*)alloc(2048ull * 1024 * 2);
  bf16* qv      = (bf16*)alloc(2048ull * 1024 * 2);
  bf16* rb      = (bf16*)alloc(1024ull * 1024 * 2);
  bf16* vT      = (bf16*)alloc(64ull * 64 * 1024 * 2);
  bf16* av      = (bf16*)alloc(2048ull * 1024 * 2);
  bf16* acat1   = (bf16*)alloc(2048ull * 2048 * 2);
  bf16* acat2   = (bf16*)alloc(2048ull * 2048 * 2);
  bf16* x2      = (bf16*)alloc(2048ull * 1024 * 2);
  char* arena   = alloc(16ull * 2048 * 1024 * 2);  // 64MB; B_pos, then reused
  bf16*  bpos = (bf16*)arena;
  float* zf   = (float*)arena;                   // [0,8M)   after attention
  float* rf   = (float*)(arena + (8ull << 20));  // [8,16M)
  float* hf   = (float*)(arena + (16ull << 20)); // [16,24M)
  float* o1   = (float*)(arena + (24ull << 20)); // [24,32M)
  bf16*  tffn = (bf16*)(arena + (32ull << 20));  // [32,48M)

  TPack tp;
  int di = 0;
  auto setd = [&](const float* s, bf16* d, int K, int N, int ldd) {
    tp.d[di].src = s; tp.d[di].dst = d; tp.d[di].K = K; tp.d[di].N = N; tp.d[di].ldd = ldd; di++;
  };
  setd(W_kv, Wkv_t, 1024, 2048, 1024);
  setd(W_q, Wq_t, 1024, 1024, 1024);
  setd(W_pos, Wpos_t, 1024, 1024, 1024);
  setd(W_proj, Wproj_t, 1024, 1024, 1024);
  setd(Wr1, Wrc1, 1024, 1024, 2048);  setd(Ur1, Wrc1 + 1024, 1024, 1024, 2048);
  setd(Wz1, Wzc1, 1024, 1024, 2048);  setd(Uz1, Wzc1 + 1024, 1024, 1024, 2048);
  setd(Wg1, Wgc1, 1024, 1024, 2048);  setd(Ug1, Wgc1 + 1024, 1024, 1024, 2048);
  setd(Wr2, Wrc2, 1024, 1024, 2048);  setd(Ur2, Wrc2 + 1024, 1024, 1024, 2048);
  setd(Wz2, Wzc2, 1024, 1024, 2048);  setd(Uz2, Wzc2 + 1024, 1024, 1024, 2048);
  setd(Wg2, Wgc2, 1024, 1024, 2048);  setd(Ug2, Wgc2 + 1024, 1024, 1024, 2048);
  setd(W1, W1t, 1024, 4096, 1024);
  setd(W2, W2t, 4096, 1024, 4096);
  wt_transpose<<<dim3(1024, 1, 18), 256, 0, stream>>>(tp);
  convertf2b<<<1024, 256, 0, stream>>>(pos_emb, posb, 1024 * 1024);
  ln1_kernel<<<4096, 256, 0, stream>>>(inputs, memory, ln1_g, ln1_b, x1, acat1 + 1024);

  auto gemm = [&](const bf16* A, int lda, const bf16* B, int ldb,
                  bf16* Cb, bf16* Cb2, float* Cf, int ldc,
                  int M, int N, int K, const float* bias, int mode,
                  int bat, long long Ab, long long Bb, long long Cbt,
                  const float* up, const float* vp) {
    GemmP p;
    p.A = A; p.B = B; p.Cb = Cb; p.Cb2 = Cb2; p.Cf = Cf;
    p.bias = bias; p.up = up; p.vp = vp;
    p.K = K; p.lda = lda; p.ldb = ldb; p.ldc = ldc;
    p.Abat = Ab; p.Bbat = Bb; p.Cbat = Cbt; p.mode = mode;
    gemm_bt<<<dim3(M / 128, N / 128, bat), 256, 0, stream>>>(p);
  };

  // projections
  gemm(x1, 1024, Wkv_t, 1024, kvb, nullptr, nullptr, 2048, 4096, 2048, 1024, b_kv, M_BF16, 1, 0, 0, 0, nullptr, nullptr);
  gemm(x1 + 2048ull * 1024, 1024, Wq_t, 1024, qu, qv, nullptr, 1024, 2048, 1024, 1024, b_q, M_QUV, 1, 0, 0, 0, u_in, v_in);
  gemm(posb, 1024, Wpos_t, 1024, rb, nullptr, nullptr, 1024, 1024, 1024, 1024, b_pos, M_BF16, 1, 0, 0, 0, nullptr, nullptr);
  transpose_v<<<dim3(16, 64), 256, 0, stream>>>(kvb, vT);
  // B_pos[h][m][j] = qv_h @ r_h^T  (batched over heads, K=64)
  gemm(qv, 1024, rb, 1024, bpos, nullptr, nullptr, 1024, 2048, 1024, 64, nullptr, M_BF16, 16, 64, 64, 2048ll * 1024, nullptr, nullptr);
  flash_attn<<<dim3(8, 64), 256, 0, stream>>>(qu, kvb, vT, bpos, av);
  // a1 = relu(av @ Wproj + b) into Acat1 cols [0,1024)
  gemm(av, 1024, Wproj_t, 1024, acat1, nullptr, nullptr, 2048, 2048, 1024, 1024, b_proj, M_BF16_RELU, 1, 0, 0, 0, nullptr, nullptr);
  // GRU1
  gemm(acat1, 2048, Wzc1, 2048, nullptr, nullptr, zf, 1024, 2048, 1024, 2048, bg1, M_SIG_NEG, 1, 0, 0, 0, nullptr, nullptr);
  gemm(acat1, 2048, Wrc1, 2048, nullptr, nullptr, rf, 1024, 2048, 1024, 2048, nullptr, M_SIG, 1, 0, 0, 0, nullptr, nullptr);
  rx_kernel<<<2048, 256, 0, stream>>>(rf, inputs, acat1 + 1024, 2048 * 1024);
  gemm(acat1, 2048, Wgc1, 2048, nullptr, nullptr, hf, 1024, 2048, 1024, 2048, nullptr, M_TANH, 1, 0, 0, 0, nullptr, nullptr);
  gru_combine_ln<<<2048, 256, 0, stream>>>(zf, hf, inputs, ln2_g, ln2_b, o1, x2, acat2 + 1024);
  // FFN
  gemm(x2, 1024, W1t, 1024, tffn, nullptr, nullptr, 4096, 2048, 4096, 1024, b1, M_BF16_RELU, 1, 0, 0, 0, nullptr, nullptr);
  gemm(tffn, 4096, W2t, 4096, acat2, nullptr, nullptr, 2048, 2048, 1024, 4096, b2, M_BF16_RELU, 1, 0, 0, 0, nullptr, nullptr);
  // GRU2
  gemm(acat2, 2048, Wzc2, 2048, nullptr, nullptr, zf, 1024, 2048, 1024, 2048, bg2, M_SIG_NEG, 1, 0, 0, 0, nullptr, nullptr);
  gemm(acat2, 2048, Wrc2, 2048, nullptr, nullptr, rf, 1024, 2048, 1024, 2048, nullptr, M_SIG, 1, 0, 0, 0, nullptr, nullptr);
  rx_kernel<<<2048, 256, 0, stream>>>(rf, o1, acat2 + 1024, 2048 * 1024);
  gemm(acat2, 2048, Wgc2, 2048, nullptr, nullptr, hf, 1024, 2048, 1024, 2048, nullptr, M_TANH, 1, 0, 0, 0, nullptr, nullptr);
  final_combine<<<2048, 256, 0, stream>>>(zf, hf, o1, (float*)d_out, 2048 * 1024);
}